// Round 11
// baseline (250.153 us; speedup 1.0000x reference)
//
#include <hip/hip_runtime.h>
#include <hip/hip_bf16.h>

// Causal MHA forward, B=4 T=2048 C=1024 H=16 D=64. fp32 in/out, bf16 MFMA inside.
// Round 15: gemm_qkv -> 256x256 phased core. Round-14 accounting showed the
// 128^2 core is LDS-READ-BW bound (192KB reads/CU/K-step vs ~320cyc MFMA);
// fix is fragment economy: per-wave 128x64 output = 0.375 ds_read_b128/MFMA
// (vs 0.75 at 64x32). 8 waves (2Mx4N), acc[8][4], LDS 128KB 2-slot dbuf,
// BK=64, 0-conflict XOR rows. Each K-step = 4 phases of 16 MFMA:
//   ph1: read B.ks0 + A.ks0(r0-3), stage A(t+1); barrier; MFMA; barrier
//   ph2: read A.ks0(r4-7),          stage B(t+1); barrier; MFMA; barrier
//   ph3: read B.ks1 + A.ks1(r0-3);                barrier; MFMA; barrier
//   ph4: read A.ks1(r4-7);  barrier; MFMA; vmcnt(0) [loads 2-3 phases old];
//        barrier  -> staged tile published for next iter, never a cold drain.
// setprio(1) around MFMA clusters (phase role-split regime, m218b).
// gemm_proj stays on the round-14 128^2 core; attn/cvt unchanged (round 14).

#define Bsz 4
#define Tsz 2048
#define Csz 1024
#define Hn  16
#define Dh  64

typedef unsigned short u16;
typedef __attribute__((ext_vector_type(8))) short bf16x8;   // 8 bf16 = 4 VGPRs
typedef __attribute__((ext_vector_type(4))) float f32x4;
typedef __attribute__((ext_vector_type(4))) unsigned int u32x4;
typedef __attribute__((ext_vector_type(2))) unsigned int u32x2;

__device__ __forceinline__ u16 f2b(float f) {
  __hip_bfloat16 h = __float2bfloat16(f);
  return *reinterpret_cast<u16*>(&h);
}

// two NON-NEGATIVE floats -> packed bf16 pair (lo in bits 15:0), round-half-up:
// one v_perm_b32 selects bytes 2,3 of (lo+0x8000) and (hi+0x8000).
__device__ __forceinline__ unsigned pk2(float lo, float hi) {
  return __builtin_amdgcn_perm(__float_as_uint(hi) + 0x8000u,
                               __float_as_uint(lo) + 0x8000u, 0x07060302u);
}

#if __has_builtin(__builtin_amdgcn_exp2f)
#define EX2(x) __builtin_amdgcn_exp2f(x)
#else
#define EX2(x) exp2f(x)
#endif

// async global->LDS, 16B per lane; lds base must be wave-uniform (lane*16 implicit)
__device__ __forceinline__ void gld_lds16(const void* g, void* lds) {
  __builtin_amdgcn_global_load_lds(
      (const __attribute__((address_space(1))) unsigned int*)g,
      (__attribute__((address_space(3))) unsigned int*)lds, 16, 0, 0);
}

// ---------------- fp32 -> bf16 elementwise (8 elems/thread) ----------------
__global__ __launch_bounds__(256) void cvt_f32_bf16(const float* __restrict__ in,
                                                    u16* __restrict__ out) {
  size_t i = ((size_t)blockIdx.x * 256 + threadIdx.x) * 8;
  f32x4 a = *(const f32x4*)(in + i);
  f32x4 b = *(const f32x4*)(in + i + 4);
  u16 r[8];
#pragma unroll
  for (int j = 0; j < 4; ++j) { r[j] = f2b(a[j]); r[4 + j] = f2b(b[j]); }
  *(u32x4*)(out + i) = *(const u32x4*)r;
}

// ---------------- fp32 (R,C) -> bf16 transposed (C,R) ----------------
__global__ __launch_bounds__(256) void cvt_transpose(const float* __restrict__ in,
                                                     u16* __restrict__ out,
                                                     int R, int C) {
  __shared__ u16 tile[64 * 66];
  const int r0 = blockIdx.x * 64, c0 = blockIdx.y * 64;
  const int tid = threadIdx.x;
#pragma unroll
  for (int i = 0; i < 16; ++i) {
    int idx = i * 256 + tid;
    int r = idx >> 6, c = idx & 63;
    tile[r * 66 + c] = f2b(in[(size_t)(r0 + r) * C + (c0 + c)]);
  }
  __syncthreads();
#pragma unroll
  for (int i = 0; i < 16; ++i) {
    int idx = i * 256 + tid;
    int c = idx >> 6, r = idx & 63;
    out[(size_t)(c0 + c) * R + (r0 + r)] = tile[r * 66 + c];
  }
}

// ================= 256x256 phased GEMM core (gemm_qkv) =================
// C[m][n] = sum_k A[m][k]*Bt[n][k], K=1024, BK=64. 512 threads = 8 waves
// (wm=w&1 -> 128-row half, wn=w>>1 -> 64-col quarter). acc[8][4] f32x4.
// LDS: Als/Bls [2][256*64] u16 (64KB each). Rows 128B, XOR seg^(row&7).
__device__ __forceinline__ void gemm256_core(const u16* __restrict__ A,
                                             const u16* __restrict__ Bt,
                                             int m0, int n0,
                                             u16* Als, u16* Bls,
                                             f32x4 acc[8][4]) {
  const int tid = threadIdx.x;           // 0..511
  const int w = tid >> 6, lane = tid & 63;
  const int wm = w & 1, wn = w >> 1;
  const int col = lane & 15, quad = lane >> 4;
#pragma unroll
  for (int mt = 0; mt < 8; ++mt)
#pragma unroll
    for (int nt = 0; nt < 4; ++nt)
      acc[mt][nt] = (f32x4){0.f, 0.f, 0.f, 0.f};

  // staging: per matrix per K-step 2048 slots of 16B = 512 thr x 4 calls.
  // slot = c*512+tid -> row = slot>>3 (0..255), physseg = slot&7;
  // global source seg = physseg ^ (row&7)  (XOR involution).
  const u16* aP[4];
  const u16* bP[4];
#pragma unroll
  for (int c = 0; c < 4; ++c) {
    int slot = c * 512 + tid;
    int trow = slot >> 3, seg = slot & 7;
    size_t off = (size_t)trow * 1024 + (size_t)((seg ^ (trow & 7)) * 8);
    aP[c] = A + (size_t)m0 * 1024 + off;
    bP[c] = Bt + (size_t)n0 * 1024 + off;
  }
  const int swz = col & 7;                       // row&7 == col&7 at read
  const int o0 = ((0 + quad) ^ swz) * 8;         // ksub 0 seg (u16 units)
  const int o1 = ((4 + quad) ^ swz) * 8;         // ksub 1 seg

  // prologue: stage K-step 0 into slot 0 (A: 4 calls, B: 4 calls)
#pragma unroll
  for (int c = 0; c < 4; ++c) {
    gld_lds16(aP[c], Als + c * 4096 + w * 512);
    gld_lds16(bP[c], Bls + c * 4096 + w * 512);
    aP[c] += 64; bP[c] += 64;
  }
  asm volatile("s_waitcnt vmcnt(0)" ::: "memory");
  __builtin_amdgcn_s_barrier();

  const int nkt = 1024 / 64;                     // 16 K-steps
  for (int t = 0; t < nkt; ++t) {
    const int cur = t & 1, nxt = cur ^ 1;
    const u16* Ac = Als + cur * 16384;
    const u16* Bc = Bls + cur * 16384;
    u16* Ad = Als + nxt * 16384;
    u16* Bd = Bls + nxt * 16384;
    const bool st = (t + 1 < nkt);

    // ---- phase 1: B.ks0 (4) + A.ks0 rows0-3 (4); stage A(t+1) ----
    bf16x8 b0[4], af[4];
#pragma unroll
    for (int nt = 0; nt < 4; ++nt)
      b0[nt] = *(const bf16x8*)(Bc + (size_t)(wn * 64 + nt * 16 + col) * 64 + o0);
#pragma unroll
    for (int mt = 0; mt < 4; ++mt)
      af[mt] = *(const bf16x8*)(Ac + (size_t)(wm * 128 + mt * 16 + col) * 64 + o0);
    if (st) {
#pragma unroll
      for (int c = 0; c < 4; ++c) {
        gld_lds16(aP[c], Ad + c * 4096 + w * 512);
        aP[c] += 64;
      }
    }
    __builtin_amdgcn_s_barrier();
    __builtin_amdgcn_s_setprio(1);
#pragma unroll
    for (int mt = 0; mt < 4; ++mt)
#pragma unroll
      for (int nt = 0; nt < 4; ++nt)
        acc[mt][nt] = __builtin_amdgcn_mfma_f32_16x16x32_bf16(af[mt], b0[nt],
                                                              acc[mt][nt], 0, 0, 0);
    __builtin_amdgcn_s_setprio(0);
    __builtin_amdgcn_s_barrier();

    // ---- phase 2: A.ks0 rows4-7 (4); stage B(t+1) ----
#pragma unroll
    for (int mt = 0; mt < 4; ++mt)
      af[mt] = *(const bf16x8*)(Ac + (size_t)(wm * 128 + (mt + 4) * 16 + col) * 64 + o0);
    if (st) {
#pragma unroll
      for (int c = 0; c < 4; ++c) {
        gld_lds16(bP[c], Bd + c * 4096 + w * 512);
        bP[c] += 64;
      }
    }
    __builtin_amdgcn_s_barrier();
    __builtin_amdgcn_s_setprio(1);
#pragma unroll
    for (int mt = 0; mt < 4; ++mt)
#pragma unroll
      for (int nt = 0; nt < 4; ++nt)
        acc[mt + 4][nt] = __builtin_amdgcn_mfma_f32_16x16x32_bf16(af[mt], b0[nt],
                                                                  acc[mt + 4][nt], 0, 0, 0);
    __builtin_amdgcn_s_setprio(0);
    __builtin_amdgcn_s_barrier();

    // ---- phase 3: B.ks1 (4) + A.ks1 rows0-3 (4) ----
#pragma unroll
    for (int nt = 0; nt < 4; ++nt)
      b0[nt] = *(const bf16x8*)(Bc + (size_t)(wn * 64 + nt * 16 + col) * 64 + o1);
#pragma unroll
    for (int mt = 0; mt < 4; ++mt)
      af[mt] = *(const bf16x8*)(Ac + (size_t)(wm * 128 + mt * 16 + col) * 64 + o1);
    __builtin_amdgcn_s_barrier();
    __builtin_amdgcn_s_setprio(1);
#pragma unroll
    for (int mt = 0; mt < 4; ++mt)
#pragma unroll
      for (int nt = 0; nt < 4; ++nt)
        acc[mt][nt] = __builtin_amdgcn_mfma_f32_16x16x32_bf16(af[mt], b0[nt],
                                                              acc[mt][nt], 0, 0, 0);
    __builtin_amdgcn_s_setprio(0);
    __builtin_amdgcn_s_barrier();

    // ---- phase 4: A.ks1 rows4-7 (4); publish staged tile at the end ----
#pragma unroll
    for (int mt = 0; mt < 4; ++mt)
      af[mt] = *(const bf16x8*)(Ac + (size_t)(wm * 128 + (mt + 4) * 16 + col) * 64 + o1);
    __builtin_amdgcn_s_barrier();
    __builtin_amdgcn_s_setprio(1);
#pragma unroll
    for (int mt = 0; mt < 4; ++mt)
#pragma unroll
      for (int nt = 0; nt < 4; ++nt)
        acc[mt + 4][nt] = __builtin_amdgcn_mfma_f32_16x16x32_bf16(af[mt], b0[nt],
                                                                  acc[mt + 4][nt], 0, 0, 0);
    __builtin_amdgcn_s_setprio(0);
    // loads were issued 2-3 phases ago -> near-zero stall here
    asm volatile("s_waitcnt vmcnt(0)" ::: "memory");
    __builtin_amdgcn_sched_barrier(0);
    __builtin_amdgcn_s_barrier();
  }
}

// GEMM1: Xb @ WqkvT^T + b -> Q (pre-scaled), K (B,H,T,D) and V^T (B,H,D,T)
// 256x256 tiles, grid (32, 12), 512 threads.
__global__ __launch_bounds__(512, 2) void gemm_qkv(const u16* __restrict__ X,
                                                   const u16* __restrict__ WT,
                                                   const float* __restrict__ bias,
                                                   u16* __restrict__ Q,
                                                   u16* __restrict__ Kc,
                                                   u16* __restrict__ Vt) {
  __shared__ __align__(16) u16 Als[2 * 256 * 64];
  __shared__ __align__(16) u16 Bls[2 * 256 * 64];
  f32x4 acc[8][4];
  const int m0 = blockIdx.x * 256, n0 = blockIdx.y * 256;
  gemm256_core(X, WT, m0, n0, Als, Bls, acc);

  const float qscale = 0.18033688011112042f;   // 1/sqrt(D) * log2(e)
  const int tid = threadIdx.x;
  const int w = tid >> 6, lane = tid & 63;
  const int wm = w & 1, wn = w >> 1;
  const int col = lane & 15, quad = lane >> 4;
#pragma unroll
  for (int mt = 0; mt < 8; ++mt)
#pragma unroll
    for (int nt = 0; nt < 4; ++nt) {
      int n = n0 + wn * 64 + nt * 16 + col;
      int s = n >> 10, hh = (n >> 6) & (Hn - 1), d = n & 63;
      int mBase = m0 + wm * 128 + mt * 16 + quad * 4;
      int b = mBase >> 11, t0 = mBase & (Tsz - 1);
      if (s == 2) {
        // V^T: (b,h,d,t) — 4 consecutive t, one 8B store
        u16 vals[4];
#pragma unroll
        for (int r = 0; r < 4; ++r) vals[r] = f2b(acc[mt][nt][r] + bias[n]);
        *(u32x2*)(Vt + ((size_t)(b * Hn + hh) * Dh + d) * Tsz + t0) =
            *(const u32x2*)vals;
      } else {
        const float scl = (s == 0) ? qscale : 1.f;
        u16* dst = (s == 0) ? Q : Kc;
#pragma unroll
        for (int r = 0; r < 4; ++r)
          dst[((size_t)(b * Hn + hh) * Tsz + (t0 + r)) * Dh + d] =
              f2b((acc[mt][nt][r] + bias[n]) * scl);
      }
    }
}

// ---------------- 128x128 GEMM core (round 14) for gemm_proj ----------------
__device__ __forceinline__ void gemm_tile_acc(const u16* __restrict__ A,
                                              const u16* __restrict__ Bt,
                                              int m0, int n0,
                                              u16* Als, u16* Bls,   // each [2][8192]
                                              f32x4 acc[4][2]) {
  const int tid = threadIdx.x;           // 0..511
  const int w = tid >> 6, lane = tid & 63;
  const int wm = w & 1, wn = w >> 1;     // 2 x 4 wave grid
  const int col = lane & 15, quad = lane >> 4;
#pragma unroll
  for (int mt = 0; mt < 4; ++mt)
#pragma unroll
    for (int nt = 0; nt < 2; ++nt)
      acc[mt][nt] = (f32x4){0.f, 0.f, 0.f, 0.f};

  const u16* asrc[2];
  const u16* bsrc[2];
#pragma unroll
  for (int c = 0; c < 2; ++c) {
    int slot = c * 512 + tid;
    int trow = slot >> 3, seg = slot & 7;
    size_t off = (size_t)trow * 1024 + (size_t)((seg ^ (trow & 7)) * 8);
    asrc[c] = A + (size_t)m0 * 1024 + off;
    bsrc[c] = Bt + (size_t)n0 * 1024 + off;
  }
  const int swz = col & 7;
  const int o0 = ((0 + quad) ^ swz) * 8;
  const int o1 = ((4 + quad) ^ swz) * 8;

#pragma unroll
  for (int c = 0; c < 2; ++c) {
    gld_lds16(asrc[c], (char*)Als + (size_t)(c * 512 + w * 64) * 16);
    gld_lds16(bsrc[c], (char*)Bls + (size_t)(c * 512 + w * 64) * 16);
    asrc[c] += 64; bsrc[c] += 64;
  }

  const int nkt = 1024 / 64;
  for (int t = 0; t < nkt; ++t) {
    asm volatile("s_waitcnt vmcnt(0)" ::: "memory");
    __builtin_amdgcn_s_barrier();
    __builtin_amdgcn_sched_barrier(0);
    const int cur = t & 1;
    if (t + 1 < nkt) {
      const int nxt = cur ^ 1;
      u16* Ad = Als + nxt * 8192;
      u16* Bd = Bls + nxt * 8192;
#pragma unroll
      for (int c = 0; c < 2; ++c) {
        gld_lds16(asrc[c], (char*)Ad + (size_t)(c * 512 + w * 64) * 16);
        gld_lds16(bsrc[c], (char*)Bd + (size_t)(c * 512 + w * 64) * 16);
        asrc[c] += 64; bsrc[c] += 64;
      }
    }
    const u16* Ac = Als + cur * 8192;
    const u16* Bc = Bls + cur * 8192;
    bf16x8 af[4][2], bfr[2][2];
#pragma unroll
    for (int mt = 0; mt < 4; ++mt) {
      const u16* r = Ac + (size_t)(wm * 64 + mt * 16 + col) * 64;
      af[mt][0] = *(const bf16x8*)(r + o0);
      af[mt][1] = *(const bf16x8*)(r + o1);
    }
#pragma unroll
    for (int nt = 0; nt < 2; ++nt) {
      const u16* r = Bc + (size_t)(wn * 32 + nt * 16 + col) * 64;
      bfr[nt][0] = *(const bf16x8*)(r + o0);
      bfr[nt][1] = *(const bf16x8*)(r + o1);
    }
#pragma unroll
    for (int kk = 0; kk < 2; ++kk)
#pragma unroll
      for (int mt = 0; mt < 4; ++mt)
#pragma unroll
        for (int nt = 0; nt < 2; ++nt)
          acc[mt][nt] = __builtin_amdgcn_mfma_f32_16x16x32_bf16(
              af[mt][kk], bfr[nt][kk], acc[mt][nt], 0, 0, 0);
  }
}

// GEMM2: Ob(8192x1024) @ WprojT(1024x1024)^T + b -> fp32 out (B,T,C)
__global__ __launch_bounds__(512, 4) void gemm_proj(const u16* __restrict__ O,
                                                    const u16* __restrict__ WT,
                                                    const float* __restrict__ bias,
                                                    float* __restrict__ out) {
  __shared__ __align__(16) u16 Als[2 * 128 * 64];
  __shared__ __align__(16) u16 Bls[2 * 128 * 64];
  f32x4 acc[4][2];
  const int m0 = blockIdx.x * 128, n0 = blockIdx.y * 128;
  gemm_tile_acc(O, WT, m0, n0, Als, Bls, acc);

  const int tid = threadIdx.x;
  const int w = tid >> 6, lane = tid & 63;
  const int wm = w & 1, wn = w >> 1;
  const int col = lane & 15, quad = lane >> 4;
#pragma unroll
  for (int mt = 0; mt < 4; ++mt)
#pragma unroll
    for (int nt = 0; nt < 2; ++nt)
#pragma unroll
      for (int r = 0; r < 4; ++r) {
        int m = m0 + wm * 64 + mt * 16 + quad * 4 + r;
        int n = n0 + wn * 32 + nt * 16 + col;
        out[(size_t)m * Csz + n] = acc[mt][nt][r] + bias[n];
      }
}

// ---------------- flash attention (round-12 form, unchanged) ----------------
__device__ __forceinline__ void attn_tile_stage(
    const u16* __restrict__ Kc, const u16* __restrict__ Vc,
    const bf16x8* aq, f32x4* oacc, float* lsum,
    bool domask, int rel, int qg, int col, int quad, int off0, int off1) {
  // S^T = K Q^T  (4 key-tiles of 16, contraction d=64 = 2 ks)
  f32x4 sacc[4];
#pragma unroll
  for (int kt = 0; kt < 4; ++kt) sacc[kt] = (f32x4){0.f, 0.f, 0.f, 0.f};
#pragma unroll
  for (int ks = 0; ks < 2; ++ks)
#pragma unroll
    for (int kt = 0; kt < 4; ++kt) {
      bf16x8 bk = *(const bf16x8*)(&Kc[(kt * 16 + col) * 64 + (ks ? off1 : off0)]);
      sacc[kt] = __builtin_amdgcn_mfma_f32_16x16x32_bf16(bk, aq[ks],
                                                         sacc[kt], 0, 0, 0);
    }

  // P^T = exp2(S^T) in registers; mask only when the stage crosses the diag
  float e[4][4];
  if (domask) {
#pragma unroll
    for (int kt = 0; kt < 4; ++kt)
#pragma unroll
      for (int r = 0; r < 4; ++r) {
        int kl = rel + kt * 16 + quad * 4 + r;    // key rel. to tile qbase
        float p = (kl > qg) ? 0.f : EX2(sacc[kt][r]);
        lsum[kt] += p;
        e[kt][r] = p;
      }
  } else {
#pragma unroll
    for (int kt = 0; kt < 4; ++kt)
#pragma unroll
      for (int r = 0; r < 4; ++r) {
        float p = EX2(sacc[kt][r]);
        lsum[kt] += p;
        e[kt][r] = p;
      }
  }

  // per 32-key half: build PV B-frag via permlane exchange, accumulate O^T
#pragma unroll
  for (int ksg = 0; ksg < 2; ++ksg) {
    // lane (col,quad) holds keys 32*ksg + {4q..4q+3} (lo kt) and +16 (hi kt)
    unsigned w00 = pk2(e[2 * ksg][0], e[2 * ksg][1]);
    unsigned w01 = pk2(e[2 * ksg][2], e[2 * ksg][3]);
    unsigned w10 = pk2(e[2 * ksg + 1][0], e[2 * ksg + 1][1]);
    unsigned w11 = pk2(e[2 * ksg + 1][2], e[2 * ksg + 1][3]);
    // 32-swap then 16-swap: word0 = keys {8q,8q+1}, word2 = {8q+4,8q+5}
    auto ra = __builtin_amdgcn_permlane32_swap(w00, w10, false, false);
    auto rb = __builtin_amdgcn_permlane32_swap(w01, w11, false, false);
    auto sa = __builtin_amdgcn_permlane16_swap(ra[0], ra[1], false, false);
    auto sb = __builtin_amdgcn_permlane16_swap(rb[0], rb[1], false, false);
    union { unsigned u[4]; bf16x8 v; } pf;
    pf.u[0] = sa[0]; pf.u[1] = sb[0]; pf.u[2] = sa[1]; pf.u[3] = sb[1];
#pragma unroll
    for (int dt = 0; dt < 4; ++dt) {
      bf16x8 bv = *(const bf16x8*)(&Vc[(dt * 16 + col) * 64 + (ksg ? off1 : off0)]);
      oacc[dt] = __builtin_amdgcn_mfma_f32_16x16x32_bf16(bv, pf.v,
                                                         oacc[dt], 0, 0, 0);
    }
  }
}

// 512 threads (8 waves x 16 rows), TWO complementary 128-row q-tiles per block
// (qlo=a, qhi=15-a of the same (b,h)); one shared K/V stream of 2*qhi+2 64-key
// stages; lo tile computes on its prefix. Per-block compute = 34 stage-units
// for every block -> perfect balance. TRIPLE-buffered async gld_lds ring:
//   iter s: s_waitcnt vmcnt(2) (own stage-s pair retired; s+1 in flight) ->
//   s_barrier -> issue DMA(s+2) -> compute. Last iter waits vmcnt(0).
// K [64 key][64 d], V^T [64 d][64 key], 128B rows XOR-swizzled seg^(row&7).
__global__ __launch_bounds__(512, 4) void attn(const u16* __restrict__ Q,
                                               const u16* __restrict__ Kg,
                                               const u16* __restrict__ Vt,
                                               u16* __restrict__ O) {
  __shared__ __align__(16) u16 Ks[3][64 * 64];      // [buf][key][d]  (DMA, swizzled segs)
  __shared__ __align__(16) u16 Vs[3][64 * 64];      // [buf][d][key]  (DMA, swizzled segs)

  // XCD clustering: d0%8 = XCD (HW round-robin). All 8 pair-blocks of one
  // (b,h) — and 8 (b,h)'s — per XCD, so K/V stays L2-resident.
  const int d0 = blockIdx.x;                        // 0..511
  const int xcd = d0 & 7;
  const int idx = d0 >> 3;                          // 0..63
  const int bh = ((idx & 7) << 3) | xcd;            // 0..63 == b*Hn + h
  const int a = idx >> 3;                           // 0..7
  const int qlo = a, qhi = 15 - a;
  const int h = bh & (Hn - 1), b = bh >> 4;

  const int tid = threadIdx.x, w = tid >> 6, lane = tid & 63;
  const int col = lane & 15, quad = lane >> 4;
  const int qbl = qlo << 7, qbh = qhi << 7;         // tile bases (128 rows)

  const u16* Kbase = Kg + (size_t)bh * Tsz * Dh;    // (key, d) rows of 64
  const u16* Vbase = Vt + (size_t)bh * Dh * Tsz;    // (d, key) rows of 2048

  // staging coords: thread tid stages 16B to LDS slot tid (row = tid>>3,
  // physseg = tid&7); source pre-swizzled: seg = physseg ^ (row&7).
  const int trow = tid >> 3;                             // 0..63
  const int xseg = ((tid & 7) ^ (trow & 7)) * 8;         // u16 units
  const size_t koff = (size_t)trow * 64 + xseg;          // within K stage tile
  const size_t voff = (size_t)trow * Tsz + xseg;         // within V rows
  const int swz = col & 7;                               // read-side XOR
  const int off0 = ((0 + quad) ^ swz) << 3;              // ks/ksg = 0
  const int off1 = ((4 + quad) ^ swz) << 3;              // ks/ksg = 1

  // Q fragments for both tiles straight from global (one-time), retired
  // BEFORE the first DMA issue so vmcnt counts only staging ops afterwards.
  bf16x8 aq_hi[2], aq_lo[2];
  {
    const u16* Qh = Q + ((size_t)bh * Tsz + qbh) * Dh;
    const u16* Ql = Q + ((size_t)bh * Tsz + qbl) * Dh;
#pragma unroll
    for (int ks = 0; ks < 2; ++ks) {
      aq_hi[ks] = *(const bf16x8*)(Qh + (size_t)(w * 16 + col) * Dh + ks * 32 + quad * 8);
      aq_lo[ks] = *(const bf16x8*)(Ql + (size_t)(w * 16 + col) * Dh + ks * 32 + quad * 8);
    }
  }
  asm volatile("s_waitcnt vmcnt(0)" ::: "memory");

  const int nst = 2 * qhi + 2;       // shared K/V stream length; >= 18
  // prologue: issue stages 0 and 1 (1 K-op + 1 V-op per thread each)
  gld_lds16(Kbase + koff, &Ks[0][w * 512]);
  gld_lds16(Vbase + voff, &Vs[0][w * 512]);
  gld_lds16(Kbase + 4096 + koff, &Ks[1][w * 512]);
  gld_lds16(Vbase + 64 + voff, &Vs[1][w * 512]);

  f32x4 oacc_hi[4], oacc_lo[4];
#pragma unroll
  for (int dt = 0; dt < 4; ++dt) {
    oacc_hi[dt] = (f32x4){0.f, 0.f, 0.f, 0.f};
    oacc_lo[dt] = (f32x4){0.f, 0.f, 0.f, 0.f};
  }
  float lsum_hi[4] = {0.f, 0.f, 0.f, 0.f};
  float lsum_lo[4] = {0.f, 0.f, 0.f, 0.f};

  // DMA source pointers for stage s+2
  const u16* kdma = Kbase + 2 * 4096 + koff;
  const u16* vdma = Vbase + 2 * 64 + voff;

  const int qg = w * 16 + col;               // lane's q row (tile-local)
  const int wge4 = (w >= 4) ? 1 : 0;
  const int smask_hi = 2 * qhi + wge4;       // first stage needing mask (hi)
  const int smask_lo = 2 * qlo + wge4;       // first stage needing mask (lo)
  const int lo_end = 2 * qlo + 1 + wge4;     // lo computes for s < lo_end
  const int hi2 = 2 * qhi, lo2 = 2 * qlo;

  int cur = 0;                       // LDS slot of stage s
  for (int s = 0; s < nst; ++s) {
    // retire own stage-s pair (oldest 2 ops); stage-s+1 stays in flight
    if (s + 1 < nst) {
      asm volatile("s_waitcnt vmcnt(2)" ::: "memory");
    } else {
      asm volatile("s_waitcnt vmcnt(0)" ::: "memory");
    }
    __builtin_amdgcn_s_barrier();       // all waves' stage-s visible; reads of
    __builtin_amdgcn_sched_barrier(0);  // stage s-1 complete -> slot reusable
    if (s + 2 < nst) {
      int pf = cur + 2; if (pf >= 3) pf -= 3;
      gld_lds16(kdma, &Ks[pf][w * 512]);
      gld_lds16(vdma, &Vs[pf][w * 512]);
      kdma += 4096;
      vdma += 64;
    }
    const u16* Kc = &Ks[cur][0];
    const u16* Vc = &Vs[cur][0];

    // hi tile: all stages; waves 0-3 skip the final (fully-masked) stage
    if (w >= 4 || s < nst - 1)
      attn_tile_stage(Kc, Vc, aq_hi, oacc_hi, lsum_hi,
                      s >= smask_hi, (s - hi2) * 64, qg, col, quad, off0, off1);
    // lo tile: prefix of the stream only
    if (s < lo_end)
      attn_tile_stage(Kc, Vc, aq_lo, oacc_lo, lsum_lo,
                      s >= smask_lo, (s - lo2) * 64, qg, col, quad, off0, off1);

    cur += 1; if (cur >= 3) cur = 0;
  }

  // l reduction per tile: merge partials, keys spread across quads -> xor 16,32
  float vh = (lsum_hi[0] + lsum_hi[1]) + (lsum_hi[2] + lsum_hi[3]);
  vh += __shfl_xor(vh, 16);
  vh += __shfl_xor(vh, 32);
  const float invh = 1.0f / vh;
  float vl = (lsum_lo[0] + lsum_lo[1]) + (lsum_lo[2] + lsum_lo[3]);
  vl += __shfl_xor(vl, 16);
  vl += __shfl_xor(vl, 32);
  const float invl = 1.0f / vl;

  // epilogue: O[b, t, h, d=dt*16+quad*4+r] = oacc^T / l, for both tiles
  const int rgh = qbh + w * 16 + col;
  const int rgl = qbl + w * 16 + col;
  u16* OrowH = O + (((size_t)b * Tsz + rgh) * Hn + h) * Dh;
  u16* OrowL = O + (((size_t)b * Tsz + rgl) * Hn + h) * Dh;
#pragma unroll
  for (int dt = 0; dt < 4; ++dt) {
    u16 vh4[4], vl4[4];
#pragma unroll
    for (int r = 0; r < 4; ++r) {
      vh4[r] = f2b(oacc_hi[dt][r] * invh);
      vl4[r] = f2b(oacc_lo[dt][r] * invl);
    }
    *(u32x2*)(OrowH + dt * 16 + quad * 4) = *(const u32x2*)vh4;
    *(u32x2*)(OrowL + dt * 16 + quad * 4) = *(const u32x2*)vl4;
  }
}

extern "C" void kernel_launch(void* const* d_in, const int* in_sizes, int n_in,
                              void* d_out, int out_size, void* d_ws, size_t ws_size,
                              hipStream_t stream) {
  const float* x      = (const float*)d_in[0];
  const float* w_qkv  = (const float*)d_in[1];
  const float* b_qkv  = (const float*)d_in[2];
  const float* w_proj = (const float*)d_in[3];
  const float* b_proj = (const float*)d_in[4];
  float* out = (float*)d_out;

  // workspace layout (u16 elements), total 72 MB
  u16* Xb     = (u16*)d_ws;                          // 8192*1024
  u16* WqkvT  = Xb + (size_t)8192 * 1024;            // 3072*1024
  u16* WprojT = WqkvT + (size_t)3072 * 1024;         // 1024*1024
  u16* Qb     = WprojT + (size_t)1024 * 1024;        // 8192*1024 (pre-scaled)
  u16* Kb     = Qb + (size_t)8192 * 1024;            // 8192*1024
  u16* Ob     = Kb + (size_t)8192 * 1024;            // 8192*1024 (B,T,H,D)
  // d_out doubles as scratch: V^T (B,H,D,T) bf16, 16 MB; overwritten by gemm_proj
  u16* Vtb    = (u16*)d_out;                         // 8192*1024

  cvt_f32_bf16<<<4096, 256, 0, stream>>>(x, Xb);
  cvt_transpose<<<dim3(16, 48), 256, 0, stream>>>(w_qkv, WqkvT, 1024, 3072);
  cvt_transpose<<<dim3(16, 16), 256, 0, stream>>>(w_proj, WprojT, 1024, 1024);
  gemm_qkv<<<dim3(32, 12), 512, 0, stream>>>(Xb, WqkvT, b_qkv, Qb, Kb, Vtb);
  attn<<<dim3(512), 512, 0, stream>>>(Qb, Kb, Vtb, Ob);
  gemm_proj<<<dim3(64, 8), 512, 0, stream>>>(Ob, WprojT, b_proj, out);
}

// Round 13
// 229.198 us; speedup vs baseline: 1.0914x; 1.0914x over previous
//
#include <hip/hip_runtime.h>
#include <hip/hip_bf16.h>

// Causal MHA forward, B=4 T=2048 C=1024 H=16 D=64. fp32 in/out, bf16 MFMA inside.
// Round 17 = round 16 resubmitted (previous bench died in the harness --
// "container failed twice" -- before producing a measurement; kernels are
// byte-identical to the passing round-14 build except the merged prep).
//  - gemm_qkv / gemm_proj: round-14 128x128 core, BK=64, 0-conflict XOR rows,
//    512 thr / 8 waves (2Mx4N, 64x32/wave), double-buffered counted ring,
//    2 blocks/CU = 16 waves/CU.
//  - attn: round-12 form (complementary q-tile pairing, triple-buffer
//    vmcnt(2) ring, perm-pack pk2, native exp2).
//  - prep: one kernel does fp32->bf16 of x (4096 blocks) + both weight
//    transposes (768 + 256 blocks) -> 6 launches cut to 4.

#define Bsz 4
#define Tsz 2048
#define Csz 1024
#define Hn  16
#define Dh  64

typedef unsigned short u16;
typedef __attribute__((ext_vector_type(8))) short bf16x8;   // 8 bf16 = 4 VGPRs
typedef __attribute__((ext_vector_type(4))) float f32x4;
typedef __attribute__((ext_vector_type(4))) unsigned int u32x4;
typedef __attribute__((ext_vector_type(2))) unsigned int u32x2;

__device__ __forceinline__ u16 f2b(float f) {
  __hip_bfloat16 h = __float2bfloat16(f);
  return *reinterpret_cast<u16*>(&h);
}

// two NON-NEGATIVE floats -> packed bf16 pair (lo in bits 15:0), round-half-up:
// one v_perm_b32 selects bytes 2,3 of (lo+0x8000) and (hi+0x8000).
__device__ __forceinline__ unsigned pk2(float lo, float hi) {
  return __builtin_amdgcn_perm(__float_as_uint(hi) + 0x8000u,
                               __float_as_uint(lo) + 0x8000u, 0x07060302u);
}

#if __has_builtin(__builtin_amdgcn_exp2f)
#define EX2(x) __builtin_amdgcn_exp2f(x)
#else
#define EX2(x) exp2f(x)
#endif

// async global->LDS, 16B per lane; lds base must be wave-uniform (lane*16 implicit)
__device__ __forceinline__ void gld_lds16(const void* g, void* lds) {
  __builtin_amdgcn_global_load_lds(
      (const __attribute__((address_space(1))) unsigned int*)g,
      (__attribute__((address_space(3))) unsigned int*)lds, 16, 0, 0);
}

// ---------------- prep: x fp32->bf16 + both weight transposes ----------------
// grid 5120 x 256 thr: blocks [0,4096) cvt x; [4096,4864) transpose w_qkv
// (1024x3072 -> 3072x1024); [4864,5120) transpose w_proj (1024x1024).
__global__ __launch_bounds__(256) void prep(const float* __restrict__ x,
                                            u16* __restrict__ Xb,
                                            const float* __restrict__ w_qkv,
                                            u16* __restrict__ WqkvT,
                                            const float* __restrict__ w_proj,
                                            u16* __restrict__ WprojT) {
  const int bid = blockIdx.x;
  const int tid = threadIdx.x;
  if (bid < 4096) {
    size_t i = ((size_t)bid * 256 + tid) * 8;
    f32x4 a = *(const f32x4*)(x + i);
    f32x4 b = *(const f32x4*)(x + i + 4);
    u16 r[8];
#pragma unroll
    for (int j = 0; j < 4; ++j) { r[j] = f2b(a[j]); r[4 + j] = f2b(b[j]); }
    *(u32x4*)(Xb + i) = *(const u32x4*)r;
    return;
  }
  __shared__ u16 tile[64 * 66];
  const float* in;
  u16* out;
  int R, C, bx, by;
  int t = bid - 4096;
  if (t < 768) {
    in = w_qkv; out = WqkvT; R = 1024; C = 3072;
    bx = t & 15; by = t >> 4;                 // 16 x 48
  } else {
    t -= 768;
    in = w_proj; out = WprojT; R = 1024; C = 1024;
    bx = t & 15; by = t >> 4;                 // 16 x 16
  }
  const int r0 = bx * 64, c0 = by * 64;
#pragma unroll
  for (int i = 0; i < 16; ++i) {
    int idx = i * 256 + tid;
    int r = idx >> 6, c = idx & 63;
    tile[r * 66 + c] = f2b(in[(size_t)(r0 + r) * C + (c0 + c)]);
  }
  __syncthreads();
#pragma unroll
  for (int i = 0; i < 16; ++i) {
    int idx = i * 256 + tid;
    int c = idx >> 6, r = idx & 63;
    out[(size_t)(c0 + c) * R + (r0 + r)] = tile[r * 66 + c];
  }
}

// ---------------- 128x128 GEMM core, BK=64, K=1024, 512 threads ----------------
// C[m][n] = sum_k A[m][k]*Bt[n][k]. Stage tiles [128 rows][64 bf16] (128B
// rows), XOR seg^(row&7) swizzled (0 bank conflicts). Double-buffered ring:
//   iter t: vmcnt(0) [tile t landed, issued one iter ago] -> s_barrier ->
//   issue DMA(t+1) into t-1's slot -> 12 ds_read_b128 + 16 MFMA per wave.
// 8 waves (2Mx4N), per-wave 64x32 output, acc[4][2] f32x4.
__device__ __forceinline__ void gemm_tile_acc(const u16* __restrict__ A,
                                              const u16* __restrict__ Bt,
                                              int m0, int n0,
                                              u16* Als, u16* Bls,   // each [2][8192]
                                              f32x4 acc[4][2]) {
  const int tid = threadIdx.x;           // 0..511
  const int w = tid >> 6, lane = tid & 63;
  const int wm = w & 1, wn = w >> 1;     // 2 x 4 wave grid
  const int col = lane & 15, quad = lane >> 4;
#pragma unroll
  for (int mt = 0; mt < 4; ++mt)
#pragma unroll
    for (int nt = 0; nt < 2; ++nt)
      acc[mt][nt] = (f32x4){0.f, 0.f, 0.f, 0.f};

  // staging: 1024 slots (128 rows x 8 segs of 16B) per matrix per K-tile;
  // 512 threads x 2 chunks. slot = c*512 + tid -> row = slot>>3, phys seg =
  // slot&7; global source seg = physseg ^ (row&7) (XOR involution).
  const u16* asrc[2];
  const u16* bsrc[2];
#pragma unroll
  for (int c = 0; c < 2; ++c) {
    int slot = c * 512 + tid;
    int trow = slot >> 3, seg = slot & 7;
    size_t off = (size_t)trow * 1024 + (size_t)((seg ^ (trow & 7)) * 8);
    asrc[c] = A + (size_t)m0 * 1024 + off;
    bsrc[c] = Bt + (size_t)n0 * 1024 + off;
  }
  const int swz = col & 7;                       // row&7 == col&7 at read
  const int o0 = ((0 + quad) ^ swz) * 8;         // kk = 0 seg
  const int o1 = ((4 + quad) ^ swz) * 8;         // kk = 1 seg

  // prologue: stage K-tile 0 into half 0 (4 loads/thread)
#pragma unroll
  for (int c = 0; c < 2; ++c) {
    gld_lds16(asrc[c], (char*)Als + (size_t)(c * 512 + w * 64) * 16);
    gld_lds16(bsrc[c], (char*)Bls + (size_t)(c * 512 + w * 64) * 16);
    asrc[c] += 64; bsrc[c] += 64;
  }

  const int nkt = 1024 / 64;                     // 16 K-tiles
  for (int t = 0; t < nkt; ++t) {
    asm volatile("s_waitcnt vmcnt(0)" ::: "memory");  // tile t landed
    __builtin_amdgcn_s_barrier();        // all waves: tile t visible, reads of
    __builtin_amdgcn_sched_barrier(0);   // tile t-1 done -> its slot reusable
    const int cur = t & 1;
    if (t + 1 < nkt) {
      const int nxt = cur ^ 1;
      u16* Ad = Als + nxt * 8192;
      u16* Bd = Bls + nxt * 8192;
#pragma unroll
      for (int c = 0; c < 2; ++c) {
        gld_lds16(asrc[c], (char*)Ad + (size_t)(c * 512 + w * 64) * 16);
        gld_lds16(bsrc[c], (char*)Bd + (size_t)(c * 512 + w * 64) * 16);
        asrc[c] += 64; bsrc[c] += 64;
      }
    }
    const u16* Ac = Als + cur * 8192;
    const u16* Bc = Bls + cur * 8192;
    bf16x8 af[4][2], bfr[2][2];
#pragma unroll
    for (int mt = 0; mt < 4; ++mt) {
      const u16* r = Ac + (size_t)(wm * 64 + mt * 16 + col) * 64;
      af[mt][0] = *(const bf16x8*)(r + o0);
      af[mt][1] = *(const bf16x8*)(r + o1);
    }
#pragma unroll
    for (int nt = 0; nt < 2; ++nt) {
      const u16* r = Bc + (size_t)(wn * 32 + nt * 16 + col) * 64;
      bfr[nt][0] = *(const bf16x8*)(r + o0);
      bfr[nt][1] = *(const bf16x8*)(r + o1);
    }
#pragma unroll
    for (int kk = 0; kk < 2; ++kk)
#pragma unroll
      for (int mt = 0; mt < 4; ++mt)
#pragma unroll
        for (int nt = 0; nt < 2; ++nt)
          acc[mt][nt] = __builtin_amdgcn_mfma_f32_16x16x32_bf16(
              af[mt][kk], bfr[nt][kk], acc[mt][nt], 0, 0, 0);
  }
}

// GEMM1: Xb @ WqkvT^T + b -> Q (pre-scaled), K (B,H,T,D) and V^T (B,H,D,T)
__global__ __launch_bounds__(512, 4) void gemm_qkv(const u16* __restrict__ X,
                                                   const u16* __restrict__ WT,
                                                   const float* __restrict__ bias,
                                                   u16* __restrict__ Q,
                                                   u16* __restrict__ Kc,
                                                   u16* __restrict__ Vt) {
  __shared__ __align__(16) u16 Als[2 * 128 * 64];
  __shared__ __align__(16) u16 Bls[2 * 128 * 64];
  f32x4 acc[4][2];
  const int m0 = blockIdx.x * 128, n0 = blockIdx.y * 128;
  gemm_tile_acc(X, WT, m0, n0, Als, Bls, acc);

  const float qscale = 0.18033688011112042f;   // 1/sqrt(D) * log2(e)
  const int tid = threadIdx.x;
  const int w = tid >> 6, lane = tid & 63;
  const int wm = w & 1, wn = w >> 1;
  const int col = lane & 15, quad = lane >> 4;
#pragma unroll
  for (int mt = 0; mt < 4; ++mt)
#pragma unroll
    for (int nt = 0; nt < 2; ++nt) {
      int n = n0 + wn * 32 + nt * 16 + col;
      int s = n >> 10, hh = (n >> 6) & (Hn - 1), d = n & 63;
      int mBase = m0 + wm * 64 + mt * 16 + quad * 4;
      int b = mBase >> 11, t0 = mBase & (Tsz - 1);
      if (s == 2) {
        // V^T: (b,h,d,t) — 4 consecutive t, one 8B store
        u16 vals[4];
#pragma unroll
        for (int r = 0; r < 4; ++r) vals[r] = f2b(acc[mt][nt][r] + bias[n]);
        *(u32x2*)(Vt + ((size_t)(b * Hn + hh) * Dh + d) * Tsz + t0) =
            *(const u32x2*)vals;
      } else {
        const float scl = (s == 0) ? qscale : 1.f;
        u16* dst = (s == 0) ? Q : Kc;
#pragma unroll
        for (int r = 0; r < 4; ++r)
          dst[((size_t)(b * Hn + hh) * Tsz + (t0 + r)) * Dh + d] =
              f2b((acc[mt][nt][r] + bias[n]) * scl);
      }
    }
}

// GEMM2: Ob(8192x1024) @ WprojT(1024x1024)^T + b -> fp32 out (B,T,C)
__global__ __launch_bounds__(512, 4) void gemm_proj(const u16* __restrict__ O,
                                                    const u16* __restrict__ WT,
                                                    const float* __restrict__ bias,
                                                    float* __restrict__ out) {
  __shared__ __align__(16) u16 Als[2 * 128 * 64];
  __shared__ __align__(16) u16 Bls[2 * 128 * 64];
  f32x4 acc[4][2];
  const int m0 = blockIdx.x * 128, n0 = blockIdx.y * 128;
  gemm_tile_acc(O, WT, m0, n0, Als, Bls, acc);

  const int tid = threadIdx.x;
  const int w = tid >> 6, lane = tid & 63;
  const int wm = w & 1, wn = w >> 1;
  const int col = lane & 15, quad = lane >> 4;
#pragma unroll
  for (int mt = 0; mt < 4; ++mt)
#pragma unroll
    for (int nt = 0; nt < 2; ++nt)
#pragma unroll
      for (int r = 0; r < 4; ++r) {
        int m = m0 + wm * 64 + mt * 16 + quad * 4 + r;
        int n = n0 + wn * 32 + nt * 16 + col;
        out[(size_t)m * Csz + n] = acc[mt][nt][r] + bias[n];
      }
}

// ---------------- flash attention (round-12 form, unchanged) ----------------
__device__ __forceinline__ void attn_tile_stage(
    const u16* __restrict__ Kc, const u16* __restrict__ Vc,
    const bf16x8* aq, f32x4* oacc, float* lsum,
    bool domask, int rel, int qg, int col, int quad, int off0, int off1) {
  // S^T = K Q^T  (4 key-tiles of 16, contraction d=64 = 2 ks)
  f32x4 sacc[4];
#pragma unroll
  for (int kt = 0; kt < 4; ++kt) sacc[kt] = (f32x4){0.f, 0.f, 0.f, 0.f};
#pragma unroll
  for (int ks = 0; ks < 2; ++ks)
#pragma unroll
    for (int kt = 0; kt < 4; ++kt) {
      bf16x8 bk = *(const bf16x8*)(&Kc[(kt * 16 + col) * 64 + (ks ? off1 : off0)]);
      sacc[kt] = __builtin_amdgcn_mfma_f32_16x16x32_bf16(bk, aq[ks],
                                                         sacc[kt], 0, 0, 0);
    }

  // P^T = exp2(S^T) in registers; mask only when the stage crosses the diag
  float e[4][4];
  if (domask) {
#pragma unroll
    for (int kt = 0; kt < 4; ++kt)
#pragma unroll
      for (int r = 0; r < 4; ++r) {
        int kl = rel + kt * 16 + quad * 4 + r;    // key rel. to tile qbase
        float p = (kl > qg) ? 0.f : EX2(sacc[kt][r]);
        lsum[kt] += p;
        e[kt][r] = p;
      }
  } else {
#pragma unroll
    for (int kt = 0; kt < 4; ++kt)
#pragma unroll
      for (int r = 0; r < 4; ++r) {
        float p = EX2(sacc[kt][r]);
        lsum[kt] += p;
        e[kt][r] = p;
      }
  }

  // per 32-key half: build PV B-frag via permlane exchange, accumulate O^T
#pragma unroll
  for (int ksg = 0; ksg < 2; ++ksg) {
    // lane (col,quad) holds keys 32*ksg + {4q..4q+3} (lo kt) and +16 (hi kt)
    unsigned w00 = pk2(e[2 * ksg][0], e[2 * ksg][1]);
    unsigned w01 = pk2(e[2 * ksg][2], e[2 * ksg][3]);
    unsigned w10 = pk2(e[2 * ksg + 1][0], e[2 * ksg + 1][1]);
    unsigned w11 = pk2(e[2 * ksg + 1][2], e[2 * ksg + 1][3]);
    // 32-swap then 16-swap: word0 = keys {8q,8q+1}, word2 = {8q+4,8q+5}
    auto ra = __builtin_amdgcn_permlane32_swap(w00, w10, false, false);
    auto rb = __builtin_amdgcn_permlane32_swap(w01, w11, false, false);
    auto sa = __builtin_amdgcn_permlane16_swap(ra[0], ra[1], false, false);
    auto sb = __builtin_amdgcn_permlane16_swap(rb[0], rb[1], false, false);
    union { unsigned u[4]; bf16x8 v; } pf;
    pf.u[0] = sa[0]; pf.u[1] = sb[0]; pf.u[2] = sa[1]; pf.u[3] = sb[1];
#pragma unroll
    for (int dt = 0; dt < 4; ++dt) {
      bf16x8 bv = *(const bf16x8*)(&Vc[(dt * 16 + col) * 64 + (ksg ? off1 : off0)]);
      oacc[dt] = __builtin_amdgcn_mfma_f32_16x16x32_bf16(bv, pf.v,
                                                         oacc[dt], 0, 0, 0);
    }
  }
}

// 512 threads (8 waves x 16 rows), TWO complementary 128-row q-tiles per block
// (qlo=a, qhi=15-a of the same (b,h)); one shared K/V stream of 2*qhi+2 64-key
// stages; lo tile computes on its prefix. Per-block compute = 34 stage-units
// for every block -> perfect balance. TRIPLE-buffered async gld_lds ring:
//   iter s: s_waitcnt vmcnt(2) (own stage-s pair retired; s+1 in flight) ->
//   s_barrier -> issue DMA(s+2) -> compute. Last iter waits vmcnt(0).
// K [64 key][64 d], V^T [64 d][64 key], 128B rows XOR-swizzled seg^(row&7).
__global__ __launch_bounds__(512, 4) void attn(const u16* __restrict__ Q,
                                               const u16* __restrict__ Kg,
                                               const u16* __restrict__ Vt,
                                               u16* __restrict__ O) {
  __shared__ __align__(16) u16 Ks[3][64 * 64];      // [buf][key][d]  (DMA, swizzled segs)
  __shared__ __align__(16) u16 Vs[3][64 * 64];      // [buf][d][key]  (DMA, swizzled segs)

  // XCD clustering: d0%8 = XCD (HW round-robin). All 8 pair-blocks of one
  // (b,h) — and 8 (b,h)'s — per XCD, so K/V stays L2-resident.
  const int d0 = blockIdx.x;                        // 0..511
  const int xcd = d0 & 7;
  const int idx = d0 >> 3;                          // 0..63
  const int bh = ((idx & 7) << 3) | xcd;            // 0..63 == b*Hn + h
  const int a = idx >> 3;                           // 0..7
  const int qlo = a, qhi = 15 - a;
  const int h = bh & (Hn - 1), b = bh >> 4;

  const int tid = threadIdx.x, w = tid >> 6, lane = tid & 63;
  const int col = lane & 15, quad = lane >> 4;
  const int qbl = qlo << 7, qbh = qhi << 7;         // tile bases (128 rows)

  const u16* Kbase = Kg + (size_t)bh * Tsz * Dh;    // (key, d) rows of 64
  const u16* Vbase = Vt + (size_t)bh * Dh * Tsz;    // (d, key) rows of 2048

  // staging coords: thread tid stages 16B to LDS slot tid (row = tid>>3,
  // physseg = tid&7); source pre-swizzled: seg = physseg ^ (row&7).
  const int trow = tid >> 3;                             // 0..63
  const int xseg = ((tid & 7) ^ (trow & 7)) * 8;         // u16 units
  const size_t koff = (size_t)trow * 64 + xseg;          // within K stage tile
  const size_t voff = (size_t)trow * Tsz + xseg;         // within V rows
  const int swz = col & 7;                               // read-side XOR
  const int off0 = ((0 + quad) ^ swz) << 3;              // ks/ksg = 0
  const int off1 = ((4 + quad) ^ swz) << 3;              // ks/ksg = 1

  // Q fragments for both tiles straight from global (one-time), retired
  // BEFORE the first DMA issue so vmcnt counts only staging ops afterwards.
  bf16x8 aq_hi[2], aq_lo[2];
  {
    const u16* Qh = Q + ((size_t)bh * Tsz + qbh) * Dh;
    const u16* Ql = Q + ((size_t)bh * Tsz + qbl) * Dh;
#pragma unroll
    for (int ks = 0; ks < 2; ++ks) {
      aq_hi[ks] = *(const bf16x8*)(Qh + (size_t)(w * 16 + col) * Dh + ks * 32 + quad * 8);
      aq_lo[ks] = *(const bf16x8*)(Ql + (size_t)(w * 16 + col) * Dh + ks * 32 + quad * 8);
    }
  }
  asm volatile("s_waitcnt vmcnt(0)" ::: "memory");

  const int nst = 2 * qhi + 2;       // shared K/V stream length; >= 18
  // prologue: issue stages 0 and 1 (1 K-op + 1 V-op per thread each)
  gld_lds16(Kbase + koff, &Ks[0][w * 512]);
  gld_lds16(Vbase + voff, &Vs[0][w * 512]);
  gld_lds16(Kbase + 4096 + koff, &Ks[1][w * 512]);
  gld_lds16(Vbase + 64 + voff, &Vs[1][w * 512]);

  f32x4 oacc_hi[4], oacc_lo[4];
#pragma unroll
  for (int dt = 0; dt < 4; ++dt) {
    oacc_hi[dt] = (f32x4){0.f, 0.f, 0.f, 0.f};
    oacc_lo[dt] = (f32x4){0.f, 0.f, 0.f, 0.f};
  }
  float lsum_hi[4] = {0.f, 0.f, 0.f, 0.f};
  float lsum_lo[4] = {0.f, 0.f, 0.f, 0.f};

  // DMA source pointers for stage s+2
  const u16* kdma = Kbase + 2 * 4096 + koff;
  const u16* vdma = Vbase + 2 * 64 + voff;

  const int qg = w * 16 + col;               // lane's q row (tile-local)
  const int wge4 = (w >= 4) ? 1 : 0;
  const int smask_hi = 2 * qhi + wge4;       // first stage needing mask (hi)
  const int smask_lo = 2 * qlo + wge4;       // first stage needing mask (lo)
  const int lo_end = 2 * qlo + 1 + wge4;     // lo computes for s < lo_end
  const int hi2 = 2 * qhi, lo2 = 2 * qlo;

  int cur = 0;                       // LDS slot of stage s
  for (int s = 0; s < nst; ++s) {
    // retire own stage-s pair (oldest 2 ops); stage-s+1 stays in flight
    if (s + 1 < nst) {
      asm volatile("s_waitcnt vmcnt(2)" ::: "memory");
    } else {
      asm volatile("s_waitcnt vmcnt(0)" ::: "memory");
    }
    __builtin_amdgcn_s_barrier();       // all waves' stage-s visible; reads of
    __builtin_amdgcn_sched_barrier(0);  // stage s-1 complete -> slot reusable
    if (s + 2 < nst) {
      int pf = cur + 2; if (pf >= 3) pf -= 3;
      gld_lds16(kdma, &Ks[pf][w * 512]);
      gld_lds16(vdma, &Vs[pf][w * 512]);
      kdma += 4096;
      vdma += 64;
    }
    const u16* Kc = &Ks[cur][0];
    const u16* Vc = &Vs[cur][0];

    // hi tile: all stages; waves 0-3 skip the final (fully-masked) stage
    if (w >= 4 || s < nst - 1)
      attn_tile_stage(Kc, Vc, aq_hi, oacc_hi, lsum_hi,
                      s >= smask_hi, (s - hi2) * 64, qg, col, quad, off0, off1);
    // lo tile: prefix of the stream only
    if (s < lo_end)
      attn_tile_stage(Kc, Vc, aq_lo, oacc_lo, lsum_lo,
                      s >= smask_lo, (s - lo2) * 64, qg, col, quad, off0, off1);

    cur += 1; if (cur >= 3) cur = 0;
  }

  // l reduction per tile: merge partials, keys spread across quads -> xor 16,32
  float vh = (lsum_hi[0] + lsum_hi[1]) + (lsum_hi[2] + lsum_hi[3]);
  vh += __shfl_xor(vh, 16);
  vh += __shfl_xor(vh, 32);
  const float invh = 1.0f / vh;
  float vl = (lsum_lo[0] + lsum_lo[1]) + (lsum_lo[2] + lsum_lo[3]);
  vl += __shfl_xor(vl, 16);
  vl += __shfl_xor(vl, 32);
  const float invl = 1.0f / vl;

  // epilogue: O[b, t, h, d=dt*16+quad*4+r] = oacc^T / l, for both tiles
  const int rgh = qbh + w * 16 + col;
  const int rgl = qbl + w * 16 + col;
  u16* OrowH = O + (((size_t)b * Tsz + rgh) * Hn + h) * Dh;
  u16* OrowL = O + (((size_t)b * Tsz + rgl) * Hn + h) * Dh;
#pragma unroll
  for (int dt = 0; dt < 4; ++dt) {
    u16 vh4[4], vl4[4];
#pragma unroll
    for (int r = 0; r < 4; ++r) {
      vh4[r] = f2b(oacc_hi[dt][r] * invh);
      vl4[r] = f2b(oacc_lo[dt][r] * invl);
    }
    *(u32x2*)(OrowH + dt * 16 + quad * 4) = *(const u32x2*)vh4;
    *(u32x2*)(OrowL + dt * 16 + quad * 4) = *(const u32x2*)vl4;
  }
}

extern "C" void kernel_launch(void* const* d_in, const int* in_sizes, int n_in,
                              void* d_out, int out_size, void* d_ws, size_t ws_size,
                              hipStream_t stream) {
  const float* x      = (const float*)d_in[0];
  const float* w_qkv  = (const float*)d_in[1];
  const float* b_qkv  = (const float*)d_in[2];
  const float* w_proj = (const float*)d_in[3];
  const float* b_proj = (const float*)d_in[4];
  float* out = (float*)d_out;

  // workspace layout (u16 elements), total 72 MB
  u16* Xb     = (u16*)d_ws;                          // 8192*1024
  u16* WqkvT  = Xb + (size_t)8192 * 1024;            // 3072*1024
  u16* WprojT = WqkvT + (size_t)3072 * 1024;         // 1024*1024
  u16* Qb     = WprojT + (size_t)1024 * 1024;        // 8192*1024 (pre-scaled)
  u16* Kb     = Qb + (size_t)8192 * 1024;            // 8192*1024
  u16* Ob     = Kb + (size_t)8192 * 1024;            // 8192*1024 (B,T,H,D)
  // d_out doubles as scratch: V^T (B,H,D,T) bf16, 16 MB; overwritten by gemm_proj
  u16* Vtb    = (u16*)d_out;                         // 8192*1024

  prep<<<5120, 256, 0, stream>>>(x, Xb, w_qkv, WqkvT, w_proj, WprojT);
  gemm_qkv<<<dim3(64, 24), 512, 0, stream>>>(Xb, WqkvT, b_qkv, Qb, Kb, Vtb);
  attn<<<dim3(512), 512, 0, stream>>>(Qb, Kb, Vtb, Ob);
  gemm_proj<<<dim3(64, 8), 512, 0, stream>>>(Ob, WprojT, b_proj, out);
}